// Round 5
// baseline (47513.730 us; speedup 1.0000x reference)
//
#include <hip/hip_runtime.h>
#include <math.h>

// Problem constants
#define Bn 256
#define Tn 128
#define En 768
#define HEn 256
#define Hn 512
#define SLOTn 120
#define INTENTn 64
#define EMBn 40
#define NEGV -1e12f

__device__ __forceinline__ float sigm(float x) { return 1.0f / (1.0f + expf(-x)); }

// ---------------------------------------------------------------------------
__global__ void zero_k(float* __restrict__ p, int n) {
    int i = blockIdx.x * blockDim.x + threadIdx.x;
    int stride = gridDim.x * blockDim.x;
    for (; i < n; i += stride) p[i] = 0.f;
}

// ---------------------------------------------------------------------------
// Detect mask dtype (jax bool as u8 vs widened int32). flag: 1 = u8.
__global__ void detect_mask_k(const unsigned char* __restrict__ m, int* __restrict__ flag) {
    __shared__ int any;
    if (threadIdx.x == 0) any = 0;
    __syncthreads();
    int found = 0;
    for (int i = threadIdx.x; i < 32768; i += 256) {
        if ((i & 3) != 0 && m[i] != 0) found = 1;
    }
    if (found) atomicOr(&any, 1);
    __syncthreads();
    if (threadIdx.x == 0) *flag = any;
}

// ---------------------------------------------------------------------------
// One-time: transpose slot_W [120][1024] -> wT4 [k4][128 s][4 q] (s padded 0)
__global__ __launch_bounds__(256) void slotwt_k(const float* __restrict__ W,
                                               float* __restrict__ wT4) {
    int idx = blockIdx.x * 256 + threadIdx.x;   // 1024*128
    int k = idx >> 7, s = idx & 127;
    float v = (s < SLOTn) ? W[(size_t)s * 1024 + k] : 0.f;
    wT4[((size_t)(k >> 2) * 128 + s) * 4 + (k & 3)] = v;
}

// ---------------------------------------------------------------------------
__device__ __forceinline__ float4 f4zero() { float4 z; z.x = z.y = z.z = z.w = 0.f; return z; }

__device__ __forceinline__ float4 enc_wload(const float* __restrict__ Wih,
                                            const float* __restrict__ Whh,
                                            int jrow, int k) {
    return (k < En) ? *(const float4*)(Wih + (size_t)jrow * En + k)
                    : *(const float4*)(Whh + (size_t)jrow * HEn + (k - En));
}

// Encoder step, both dirs. GEMM: weights LDS-staged (reg-dbuf), activations via
// wave-uniform s_load (SGPR operand). Tile 32b x 64col(16jl x 4gate), 256 thr.
// grid (16, 8, 2)
__global__ __launch_bounds__(256) void enc_step_k(
    const float* __restrict__ seq,
    const float* __restrict__ Wf_ih, const float* __restrict__ Wf_hh,
    const float* __restrict__ bf_ih, const float* __restrict__ bf_hh,
    const float* __restrict__ Wb_ih, const float* __restrict__ Wb_hh,
    const float* __restrict__ bb_ih, const float* __restrict__ bb_hh,
    const float* __restrict__ hf_in, float* __restrict__ hf_out, float* __restrict__ cf,
    const float* __restrict__ hb_in, float* __restrict__ hb_out, float* __restrict__ cb,
    float* __restrict__ enc, int step)
{
    const int dir = blockIdx.z;
    const float* __restrict__ Wih = dir ? Wb_ih : Wf_ih;
    const float* __restrict__ Whh = dir ? Wb_hh : Wf_hh;
    const float* __restrict__ bih = dir ? bb_ih : bf_ih;
    const float* __restrict__ bhh = dir ? bb_hh : bf_hh;
    const float* __restrict__ h_in = dir ? hb_in : hf_in;
    float* __restrict__ h_out = dir ? hb_out : hf_out;
    float* __restrict__ c_st  = dir ? cb : cf;
    const int t_eff = dir ? (Tn - 1 - step) : step;

    const int jb = blockIdx.x;
    const int b0 = blockIdx.y << 5;
    const int tid = threadIdx.x;
    const int c   = tid & 63;                                   // gate = c>>4, jl = c&15
    const int wid = __builtin_amdgcn_readfirstlane(tid >> 6);   // wave-uniform
    const int bw  = b0 + (wid << 3);                            // wave's first b row

    __shared__ float Bs[64][44];
    __shared__ float Gs[32][68];

    // staging assignment (2 float4 per thread per k-tile)
    const int c0_ = tid >> 3,          kq0 = tid & 7;
    const int c1_ = (tid + 256) >> 3,  kq1 = tid & 7;
    const int j0row = ((c0_ >> 4) << 8) + (jb << 4) + (c0_ & 15);
    const int j1row = ((c1_ >> 4) << 8) + (jb << 4) + (c1_ & 15);

    float acc[8] = {0,0,0,0,0,0,0,0};
    float4 r0 = enc_wload(Wih, Whh, j0row, kq0 * 4);
    float4 r1 = enc_wload(Wih, Whh, j1row, kq1 * 4);

    for (int kt = 0; kt < 32; ++kt) {               // K = 1024
        const int k0 = kt << 5;
        __syncthreads();
        *(float4*)&Bs[c0_][kq0 * 4] = r0;
        *(float4*)&Bs[c1_][kq1 * 4] = r1;
        __syncthreads();
        if (kt < 31) {
            r0 = enc_wload(Wih, Whh, j0row, k0 + 32 + kq0 * 4);
            r1 = enc_wload(Wih, Whh, j1row, k0 + 32 + kq1 * 4);
        }
#pragma unroll
        for (int g = 0; g < 8; ++g) {
            const int kk = k0 + (g << 2);
            const float* __restrict__ abase;
            size_t astr;
            if (kk < En) { abase = seq + ((size_t)bw * Tn + t_eff) * En + kk; astr = (size_t)Tn * En; }
            else         { abase = h_in + ((size_t)bw << 8) + (kk - En);      astr = HEn; }
            float4 bf = *(const float4*)&Bs[c][g << 2];
#pragma unroll
            for (int i = 0; i < 8; ++i) {
                float4 a = *(const float4*)(abase + (size_t)i * astr);  // uniform -> s_load
                acc[i] += a.x * bf.x + a.y * bf.y + a.z * bf.z + a.w * bf.w;
            }
        }
    }

#pragma unroll
    for (int i = 0; i < 8; ++i) Gs[(wid << 3) + i][c] = acc[i];
    __syncthreads();

#pragma unroll
    for (int r = 0; r < 2; ++r) {
        int p = tid + (r << 8);
        int row = p >> 4, jl = p & 15;
        int jg = (jb << 4) + jl;
        int b = b0 + row;
        float gi = Gs[row][jl]      + bih[jg]           + bhh[jg];
        float gf = Gs[row][16 + jl] + bih[HEn + jg]     + bhh[HEn + jg];
        float gg = Gs[row][32 + jl] + bih[2 * HEn + jg] + bhh[2 * HEn + jg];
        float go = Gs[row][48 + jl] + bih[3 * HEn + jg] + bhh[3 * HEn + jg];
        float ii = sigm(gi), ff = sigm(gf), tg = tanhf(gg), oo = sigm(go);
        int ci = (b << 8) + jg;
        float cn = ff * c_st[ci] + ii * tg;
        float hn = oo * tanhf(cn);
        c_st[ci] = cn;
        h_out[ci] = hn;
        enc[((size_t)t_eff * Bn + b) * Hn + dir * HEn + jg] = hn;
    }
}

// ---------------------------------------------------------------------------
// energiesT[b][j][t] (attn_b dropped: softmax shift-invariant). K-tile 32.
__global__ __launch_bounds__(256) void energT_k(
    const float* __restrict__ enc, const float* __restrict__ attn_W,
    float* __restrict__ energT)
{
    const int nb = blockIdx.x;
    const int mb = blockIdx.y;
    const int t = mb >> 2, b0 = (mb & 3) << 6;
    const int tid = threadIdx.x;
    const int tx = tid & 15, ty = tid >> 4;
    __shared__ float As[32][68];
    __shared__ float Bs[32][68];
    float acc[4][4] = {};
    for (int kt = 0; kt < 16; ++kt) {
        int k0 = kt << 5;
#pragma unroll
        for (int r = 0; r < 8; ++r) {
            int idx = tid + (r << 8);
            int kk = idx & 31, row = idx >> 5;
            As[kk][row] = enc[((size_t)t * Bn + b0 + row) * Hn + k0 + kk];
            Bs[kk][row] = attn_W[(nb * 64 + row) * Hn + k0 + kk];
        }
        __syncthreads();
#pragma unroll
        for (int kk = 0; kk < 32; ++kk) {
            float a0 = As[kk][ty * 4], a1 = As[kk][ty * 4 + 1];
            float a2 = As[kk][ty * 4 + 2], a3 = As[kk][ty * 4 + 3];
            float w0 = Bs[kk][tx * 4], w1 = Bs[kk][tx * 4 + 1];
            float w2 = Bs[kk][tx * 4 + 2], w3 = Bs[kk][tx * 4 + 3];
            acc[0][0] += a0 * w0; acc[0][1] += a0 * w1; acc[0][2] += a0 * w2; acc[0][3] += a0 * w3;
            acc[1][0] += a1 * w0; acc[1][1] += a1 * w1; acc[1][2] += a1 * w2; acc[1][3] += a1 * w3;
            acc[2][0] += a2 * w0; acc[2][1] += a2 * w1; acc[2][2] += a2 * w2; acc[2][3] += a2 * w3;
            acc[3][0] += a3 * w0; acc[3][1] += a3 * w1; acc[3][2] += a3 * w2; acc[3][3] += a3 * w3;
        }
        __syncthreads();
    }
#pragma unroll
    for (int i = 0; i < 4; ++i)
#pragma unroll
        for (int q = 0; q < 4; ++q)
            energT[((size_t)(b0 + ty * 4 + i) * Hn + nb * 64 + tx * 4 + q) * Tn + t] = acc[i][q];
}

// ---------------------------------------------------------------------------
__global__ __launch_bounds__(64) void init2_k(
    const int* __restrict__ nwp, const float* __restrict__ enc,
    const float* __restrict__ emb_table,
    float* __restrict__ ctx0, float* __restrict__ embb)
{
    int b = blockIdx.x;
    int lane = threadIdx.x;
    int p1 = (nwp[b * Tn + lane] != 0);
    int p2 = (nwp[b * Tn + lane + 64] != 0);
    unsigned long long m1 = __ballot(p1), m2 = __ballot(p2);
    int cnt = __popcll(m1) + __popcll(m2);
    int idx = cnt < (Tn - 1) ? cnt : (Tn - 1);
#pragma unroll
    for (int r = 0; r < 8; ++r) {
        int j = lane + (r << 6);
        ctx0[(b << 9) + j] = enc[((size_t)idx * Bn + b) * Hn + j];
    }
    if (lane < EMBn) embb[b * EMBn + lane] = emb_table[SLOTn * EMBn + lane];
}

// ---------------------------------------------------------------------------
__device__ __forceinline__ float4 dec_wload(const float* __restrict__ Wih,
                                            const float* __restrict__ Whh,
                                            int jrow, int k) {
    if (k < 1064) return *(const float4*)(Wih + (size_t)jrow * 1064 + k);
    if (k < 1576) return *(const float4*)(Whh + ((size_t)jrow << 9) + (k - 1064));
    return f4zero();
}

// Decoder LSTM step, same SGPR-act structure. K = 1576 (50 tiles of 32).
// grid (32, 8), 256 thr.
__global__ __launch_bounds__(256) void dec_step_k(
    const float* __restrict__ embb, const float* __restrict__ ctx_in,
    const float* __restrict__ enc, const float* __restrict__ h_in,
    float* __restrict__ h_out, float* __restrict__ c_st,
    const float* __restrict__ Wih, const float* __restrict__ Whh,
    const float* __restrict__ bih, const float* __restrict__ bhh,
    float* __restrict__ h0_out, int step)
{
    const int jb = blockIdx.x;
    const int b0 = blockIdx.y << 5;
    const int tid = threadIdx.x;
    const int c   = tid & 63;
    const int wid = __builtin_amdgcn_readfirstlane(tid >> 6);
    const int bw  = b0 + (wid << 3);

    __shared__ float Bs[64][44];
    __shared__ float Gs[32][68];

    const int c0_ = tid >> 3,          kq0 = tid & 7;
    const int c1_ = (tid + 256) >> 3,  kq1 = tid & 7;
    const int j0row = ((c0_ >> 4) << 9) + (jb << 4) + (c0_ & 15);
    const int j1row = ((c1_ >> 4) << 9) + (jb << 4) + (c1_ & 15);

    float acc[8] = {0,0,0,0,0,0,0,0};
    float4 r0 = dec_wload(Wih, Whh, j0row, kq0 * 4);
    float4 r1 = dec_wload(Wih, Whh, j1row, kq1 * 4);

    for (int kt = 0; kt < 50; ++kt) {               // 50*32 = 1600 >= 1576
        const int k0 = kt << 5;
        __syncthreads();
        *(float4*)&Bs[c0_][kq0 * 4] = r0;
        *(float4*)&Bs[c1_][kq1 * 4] = r1;
        __syncthreads();
        if (kt < 49) {
            r0 = dec_wload(Wih, Whh, j0row, k0 + 32 + kq0 * 4);
            r1 = dec_wload(Wih, Whh, j1row, k0 + 32 + kq1 * 4);
        }
#pragma unroll
        for (int g = 0; g < 8; ++g) {
            const int kk = k0 + (g << 2);
            if (kk < 1576) {
                const float* __restrict__ abase;
                size_t astr;
                if (kk < 40)        { abase = embb   + (size_t)bw * EMBn + kk;               astr = EMBn; }
                else if (kk < 552)  { abase = ctx_in + ((size_t)bw << 9) + (kk - 40);        astr = Hn; }
                else if (kk < 1064) { abase = enc + ((size_t)step * Bn + bw) * Hn + (kk - 552); astr = Hn; }
                else                { abase = h_in  + ((size_t)bw << 9) + (kk - 1064);       astr = Hn; }
                float4 bf = *(const float4*)&Bs[c][g << 2];
#pragma unroll
                for (int i = 0; i < 8; ++i) {
                    float4 a = *(const float4*)(abase + (size_t)i * astr);  // uniform -> s_load
                    acc[i] += a.x * bf.x + a.y * bf.y + a.z * bf.z + a.w * bf.w;
                }
            }
        }
    }

#pragma unroll
    for (int i = 0; i < 8; ++i) Gs[(wid << 3) + i][c] = acc[i];
    __syncthreads();

#pragma unroll
    for (int r = 0; r < 2; ++r) {
        int p = tid + (r << 8);
        int row = p >> 4, jl = p & 15;
        int jg = (jb << 4) + jl;
        int b = b0 + row;
        float gi = Gs[row][jl]      + bih[jg]          + bhh[jg];
        float gf = Gs[row][16 + jl] + bih[Hn + jg]     + bhh[Hn + jg];
        float gg = Gs[row][32 + jl] + bih[2 * Hn + jg] + bhh[2 * Hn + jg];
        float go = Gs[row][48 + jl] + bih[3 * Hn + jg] + bhh[3 * Hn + jg];
        float ii = sigm(gi), ff = sigm(gf), tg = tanhf(gg), oo = sigm(go);
        int ci = (b << 9) + jg;
        float cn = ff * c_st[ci] + ii * tg;
        float hn = oo * tanhf(cn);
        c_st[ci] = cn;
        h_out[ci] = hn;
        if (h0_out) h0_out[ci] = hn;
    }
}

// ---------------------------------------------------------------------------
// Fused per-step: blocks [0,256) attention (1 b each); [256,288) slot head
// (8 b each, acts via s_load, weights pre-transposed wT4).
__global__ __launch_bounds__(256) void dec_attn_slot_k(
    const float* __restrict__ enc, const float* __restrict__ energT,
    const float* __restrict__ h, const float* __restrict__ ctx_in,
    float* __restrict__ ctx_out, const unsigned char* __restrict__ mask_u8,
    const int* __restrict__ mask_i32, const int* __restrict__ mask_flag,
    const float* __restrict__ wT4, const float* __restrict__ slot_b,
    const float* __restrict__ emb_table, float* __restrict__ embb,
    float* __restrict__ out_slot, float* __restrict__ ctx0_save, int step)
{
    __shared__ float hs[512];
    __shared__ float red2[8][132];
    __shared__ float es[128];
    __shared__ float redm[2];
    __shared__ float ctxp[2][512];
    __shared__ float pacc[2][8][132];
    __shared__ float sc[8][132];
    __shared__ float logZ[8];
    __shared__ int amax[8];

    const int bid = blockIdx.x;
    const int tid = threadIdx.x;

    if (bid < Bn) {
        // ---------------- attention for batch b ----------------
        const int b = bid;
        hs[tid] = h[(b << 9) + tid];
        hs[tid + 256] = h[(b << 9) + 256 + tid];
        __syncthreads();
        {   // e[t'] = sum_j energT[b][j][t'] * h[j]; j split 8 ways, t' x4 per lane
            const int tg = tid & 31, jg = tid >> 5;
            const float* __restrict__ ep = energT + ((size_t)b * Hn + jg * 64) * Tn + (tg << 2);
            float4 a = f4zero();
#pragma unroll 8
            for (int jj = 0; jj < 64; ++jj) {
                float hv = hs[jg * 64 + jj];
                float4 e4 = *(const float4*)(ep + (size_t)jj * Tn);
                a.x += e4.x * hv; a.y += e4.y * hv; a.z += e4.z * hv; a.w += e4.w * hv;
            }
            *(float4*)&red2[jg][tg << 2] = a;
        }
        __syncthreads();
        if (tid < 128) {
            float e = 0.f;
#pragma unroll
            for (int jg = 0; jg < 8; ++jg) e += red2[jg][tid];
            bool mv = (*mask_flag) ? (mask_u8[(size_t)b * Tn + tid] != 0)
                                   : (mask_i32[(size_t)b * Tn + tid] != 0);
            es[tid] = mv ? NEGV : e;
        }
        __syncthreads();
        if (tid < 64) {
            float v = fmaxf(es[tid], es[tid + 64]);
            for (int o = 32; o; o >>= 1) v = fmaxf(v, __shfl_down(v, o));
            if (tid == 0) redm[0] = v;
        }
        __syncthreads();
        float m = redm[0];
        if (tid < 128) es[tid] = __expf(es[tid] - m);
        __syncthreads();
        if (tid < 64) {
            float v = es[tid] + es[tid + 64];
            for (int o = 32; o; o >>= 1) v += __shfl_down(v, o);
            if (tid == 0) redm[0] = v;
        }
        __syncthreads();
        float inv = 1.0f / redm[0];
        if (tid < 128) es[tid] *= inv;
        __syncthreads();
        {   // ctx[d] = sum_t' alpha * enc[t'][b][d]; t' split 2, d x4 per lane
            const int dq = tid & 127, th = tid >> 7;
            const int d = dq << 2;
            const float* __restrict__ ep2 = enc + (b << 9) + d;
            float4 a = f4zero();
            const int tbase = th << 6;
#pragma unroll 8
            for (int t2 = 0; t2 < 64; ++t2) {
                float al = es[tbase + t2];
                float4 e4 = *(const float4*)(ep2 + (size_t)(tbase + t2) * (Bn * Hn));
                a.x += al * e4.x; a.y += al * e4.y; a.z += al * e4.z; a.w += al * e4.w;
            }
            *(float4*)&ctxp[th][d] = a;
        }
        __syncthreads();
        {
            float v0 = ctxp[0][tid] + ctxp[1][tid];
            float v1 = ctxp[0][tid + 256] + ctxp[1][tid + 256];
            ctx_out[(b << 9) + tid] = v0;
            ctx_out[(b << 9) + 256 + tid] = v1;
            if (ctx0_save) {
                ctx0_save[(b << 9) + tid] = v0;
                ctx0_save[(b << 9) + 256 + tid] = v1;
            }
        }
    } else {
        // ---------------- slot head for 8 batches ----------------
        const int b_base = (bid - Bn) << 3;
        const int sl = tid & 127;
        const int kg = __builtin_amdgcn_readfirstlane(tid >> 7);   // 0: h half, 1: ctx half
        const float* __restrict__ a0 = (kg ? ctx_in : h) + ((size_t)b_base << 9);
        const float* __restrict__ wb = wT4 + (size_t)kg * 128 * 128 * 4;
        float acc[8] = {0,0,0,0,0,0,0,0};
        for (int k4 = 0; k4 < 128; ++k4) {
            const int k = k4 << 2;
            float4 w4 = *(const float4*)(wb + ((size_t)k4 * 128 + sl) * 4);
#pragma unroll
            for (int i = 0; i < 8; ++i) {
                const float* __restrict__ ar = a0 + ((size_t)i << 9) + k;  // uniform -> s_load
                acc[i] += w4.x * ar[0] + w4.y * ar[1] + w4.z * ar[2] + w4.w * ar[3];
            }
        }
#pragma unroll
        for (int i = 0; i < 8; ++i) pacc[kg][i][sl] = acc[i];
        __syncthreads();
        if (tid < 128) {
            float sb = (tid < SLOTn) ? slot_b[tid] : 0.f;
#pragma unroll
            for (int i = 0; i < 8; ++i)
                sc[i][tid] = pacc[0][i][tid] + pacc[1][i][tid] + sb;
        }
        __syncthreads();
        if (tid < 8) {
            float mm = -INFINITY; int am = 0;
            for (int ss = 0; ss < SLOTn; ++ss) {
                float v = sc[tid][ss];
                if (v > mm) { mm = v; am = ss; }
            }
            float sum = 0.f;
            for (int ss = 0; ss < SLOTn; ++ss) sum += __expf(sc[tid][ss] - mm);
            logZ[tid] = mm + logf(sum);
            amax[tid] = am;
        }
        __syncthreads();
        for (int r = 0; r < 4; ++r) {
            int idx = tid + (r << 8);
            int bl = idx >> 7, ss = idx & 127;
            if (ss < SLOTn)
                out_slot[(size_t)(b_base + bl) * Tn * SLOTn + step * SLOTn + ss] =
                    sc[bl][ss] - logZ[bl];
        }
        // 8*EMBn = 320 > 256 threads -> stride loop
        for (int i = tid; i < 8 * EMBn; i += 256) {
            int bl = i / EMBn, e2 = i % EMBn;
            embb[(b_base + bl) * EMBn + e2] = emb_table[amax[bl] * EMBn + e2];
        }
    }
}

// ---------------------------------------------------------------------------
__global__ __launch_bounds__(256) void intent_k(
    const float* __restrict__ h0, const float* __restrict__ ctx0,
    const float* __restrict__ W, const float* __restrict__ bias,
    float* __restrict__ out)
{
    __shared__ float ins[8][1032];
    __shared__ float Ws[16][68];
    const int tid = threadIdx.x;
    const int b_base = blockIdx.x << 3;
    for (int r = 0; r < 32; ++r) {
        int idx = tid + (r << 8);
        int bl = idx >> 10, k = idx & 1023;
        int b = b_base + bl;
        ins[bl][k] = (k < 512) ? h0[(b << 9) + k] : ctx0[(b << 9) + (k - 512)];
    }
    __syncthreads();
    const int n = tid & 63, bq = tid >> 6;
    float acc0 = 0.f, acc1 = 0.f;
    for (int kt = 0; kt < 64; ++kt) {
        int k0 = kt << 4;
#pragma unroll
        for (int r = 0; r < 4; ++r) {
            int idx = tid + (r << 8);
            int kk = idx & 15, nn = idx >> 4;
            Ws[kk][nn] = W[nn * 1024 + k0 + kk];
        }
        __syncthreads();
#pragma unroll
        for (int kk = 0; kk < 16; ++kk) {
            float w = Ws[kk][n];
            acc0 += w * ins[bq * 2][k0 + kk];
            acc1 += w * ins[bq * 2 + 1][k0 + kk];
        }
        __syncthreads();
    }
    out[(b_base + bq * 2) * INTENTn + n] = acc0 + bias[n];
    out[(b_base + bq * 2 + 1) * INTENTn + n] = acc1 + bias[n];
}

// ---------------------------------------------------------------------------
extern "C" void kernel_launch(void* const* d_in, const int* in_sizes, int n_in,
                              void* d_out, int out_size, void* d_ws, size_t ws_size,
                              hipStream_t stream) {
    (void)in_sizes; (void)n_in; (void)out_size; (void)ws_size;

    const float* seq      = (const float*)d_in[0];
    const int*   nwp      = (const int*)d_in[1];
    const unsigned char* mask_u8 = (const unsigned char*)d_in[2];
    const int*   mask_i32 = (const int*)d_in[2];
    const float* embt     = (const float*)d_in[3];
    const float* Wf_ih    = (const float*)d_in[4];
    const float* Wf_hh    = (const float*)d_in[5];
    const float* bf_ih    = (const float*)d_in[6];
    const float* bf_hh    = (const float*)d_in[7];
    const float* Wb_ih    = (const float*)d_in[8];
    const float* Wb_hh    = (const float*)d_in[9];
    const float* bb_ih    = (const float*)d_in[10];
    const float* bb_hh    = (const float*)d_in[11];
    const float* Wd_ih    = (const float*)d_in[12];
    const float* Wd_hh    = (const float*)d_in[13];
    const float* bd_ih    = (const float*)d_in[14];
    const float* bd_hh    = (const float*)d_in[15];
    const float* attn_W   = (const float*)d_in[16];
    // d_in[17] = attn_b: unused (softmax shift invariance)
    const float* slot_W   = (const float*)d_in[18];
    const float* slot_b   = (const float*)d_in[19];
    const float* intent_W = (const float*)d_in[20];
    const float* intent_b = (const float*)d_in[21];

    float* Wp = (float*)d_ws;
    size_t off = 0;
    float* enc    = Wp + off; off += (size_t)Tn * Bn * Hn;   // [T,B,512]
    float* energT = Wp + off; off += (size_t)Bn * Hn * Tn;   // [B,512,T]
    float* zbase  = Wp + off;                                 // zeroed region:
    float* hf0 = Wp + off; off += Bn * HEn;
    float* hf1 = Wp + off; off += Bn * HEn;
    float* cf  = Wp + off; off += Bn * HEn;
    float* hb0 = Wp + off; off += Bn * HEn;
    float* hb1 = Wp + off; off += Bn * HEn;
    float* cb  = Wp + off; off += Bn * HEn;
    float* hd0 = Wp + off; off += Bn * Hn;
    float* hd1 = Wp + off; off += Bn * Hn;
    float* cd  = Wp + off; off += Bn * Hn;
    int nzero = (int)(Wp + off - zbase);
    float* ctx0b = Wp + off; off += Bn * Hn;
    float* ctx1b = Wp + off; off += Bn * Hn;
    float* h0s   = Wp + off; off += Bn * Hn;
    float* ctx0s = Wp + off; off += Bn * Hn;
    float* embb  = Wp + off; off += Bn * EMBn;
    int* mask_flag = (int*)(Wp + off); off += 1;
    float* wT4   = Wp + off; off += 1024 * 128;               // slot_W transposed

    float* out = (float*)d_out;

    zero_k<<<512, 256, 0, stream>>>(zbase, nzero);
    detect_mask_k<<<1, 256, 0, stream>>>(mask_u8, mask_flag);
    slotwt_k<<<512, 256, 0, stream>>>(slot_W, wT4);

    // -------- encoder --------
    for (int s = 0; s < Tn; ++s) {
        const float* hinf = (s & 1) ? hf1 : hf0;
        float* houtf      = (s & 1) ? hf0 : hf1;
        const float* hinb = (s & 1) ? hb1 : hb0;
        float* houtb      = (s & 1) ? hb0 : hb1;
        enc_step_k<<<dim3(16, 8, 2), 256, 0, stream>>>(
            seq, Wf_ih, Wf_hh, bf_ih, bf_hh, Wb_ih, Wb_hh, bb_ih, bb_hh,
            hinf, houtf, cf, hinb, houtb, cb, enc, s);
    }

    energT_k<<<dim3(8, 512), 256, 0, stream>>>(enc, attn_W, energT);
    init2_k<<<256, 64, 0, stream>>>(nwp, enc, embt, ctx0b, embb);

    // -------- decoder --------
    for (int t = 0; t < Tn; ++t) {
        const float* ctxin = (t & 1) ? ctx1b : ctx0b;
        float* ctxout      = (t & 1) ? ctx0b : ctx1b;
        const float* hin   = (t & 1) ? hd1 : hd0;
        float* hout        = (t & 1) ? hd0 : hd1;
        dec_step_k<<<dim3(32, 8), 256, 0, stream>>>(
            embb, ctxin, enc, hin, hout, cd,
            Wd_ih, Wd_hh, bd_ih, bd_hh, (t == 0) ? h0s : (float*)nullptr, t);
        dec_attn_slot_k<<<288, 256, 0, stream>>>(
            enc, energT, hout, ctxin, ctxout, mask_u8, mask_i32, mask_flag,
            wT4, slot_b, embt, embb, out, (t == 0) ? ctx0s : (float*)nullptr, t);
    }

    intent_k<<<32, 256, 0, stream>>>(h0s, ctx0s, intent_W, intent_b,
                                     out + (size_t)Bn * Tn * SLOTn);
}